// Round 2
// baseline (1448.135 us; speedup 1.0000x reference)
//
#include <hip/hip_runtime.h>

// ---------------------------------------------------------------------------
// RowLSTM on MI355X — round 2: barrier-free wave-private column ownership.
//   prep_kernel : pack bf16 MFMA A-fragments (compressed K=40 as ks0[32]+ks1[8])
//                 for w_cell (gate-interleaved permutation) and the 1x3 row
//                 convs decomposed into 3 dx-shifted K=40 GEMMs.
//   conv7_kernel: 7x7 convs (full + mask-A) -> is_ws[b][t][mt][gate][wv][lane]
//                 so rnn's x loads are 256B-coalesced per (mt,gate).
//   rnn_kernel  : 16 blocks x 256 thr (4 waves). Wave wv owns columns
//                 [16wv,16wv+16). State lives transposed in LDS [n][ch]
//                 (stride 56 bf16 = 28 dwords -> 2-way conflicts = free).
//                 Layer loop is barrier-free (wave-synchronous LDS); ONE
//                 __syncthreads per row (halo exchange for the 1x3 convs).
//                 Gates are lane-local: lane's 4 acc regs = (i,f,o,g) of one
//                 cell channel; c carried in registers across layers.
//   out_kernel  : 1x1 conv 40->256 + ReLU, fp32 register-tiled.
// ---------------------------------------------------------------------------

typedef __bf16 bf16x8 __attribute__((ext_vector_type(8)));
typedef float  f32x4  __attribute__((ext_vector_type(4)));

#define ST_STRIDE 56           // bf16 elems; 112 B rows (16B aligned, 28 dw)
#define LOG2E 1.442695040889f

// ---------------------------------------------------------------------------
// wsA global layout (bf16):
//   [0      , 35840) cell ks0 : [(l*10+mt)][lane][j]   (k = quad*8+j, 0..31)
//   [35840  , 44800) cell ks1 : [(l*10+mt)][l16 ][j]   (k = 32+j, q==0 lanes)
//   [44800  , 54016) conv ks0 : [((cv*3+dx)*3+mtc)][lane][j]
//   [54016  , 56320) conv ks1 : [((cv*3+dx)*3+mtc)][l16 ][j]
__global__ __launch_bounds__(256) void prep_kernel(
        const float* __restrict__ wcell, const float* __restrict__ wrh,
        const float* __restrict__ wrc, __bf16* __restrict__ wsA) {
    int i = blockIdx.x * 256 + threadIdx.x;
    if (i >= 56320) return;
    float val = 0.0f;
    if (i < 35840) {                       // cell ks0
        int j = i & 7, lane = (i >> 3) & 63, lm = i >> 9;
        int mt = lm % 10, l = lm / 10;
        int k = (lane >> 4) * 8 + j, m = lane & 15;
        int row = (m & 3) * 40 + 4 * mt + (m >> 2);  // gate*40 + cc
        val = wcell[(l * 160 + row) * 40 + k];
    } else if (i < 44800) {                // cell ks1
        int i2 = i - 35840;
        int j = i2 & 7, m = (i2 >> 3) & 15, lm = i2 >> 7;
        int mt = lm % 10, l = lm / 10;
        int k = 32 + j;
        int row = (m & 3) * 40 + 4 * mt + (m >> 2);
        val = wcell[(l * 160 + row) * 40 + k];
    } else if (i < 54016) {                // conv ks0
        int i3 = i - 44800;
        int j = i3 & 7, lane = (i3 >> 3) & 63, idx = i3 >> 9;  // 0..17
        int mtc = idx % 3, t2 = idx / 3, dx = t2 % 3, cv = t2 / 3;
        int k = (lane >> 4) * 8 + j, m = lane & 15;
        int ch = (m >> 2) + 16 * mtc + 4 * (m & 3);
        const float* wsrc = cv ? wrc : wrh;    // [40][40][1][3]
        if (ch < 40) val = wsrc[(ch * 40 + k) * 3 + dx];
    } else {                               // conv ks1
        int i4 = i - 54016;
        int j = i4 & 7, m = (i4 >> 3) & 15, idx = i4 >> 7;
        int mtc = idx % 3, t2 = idx / 3, dx = t2 % 3, cv = t2 / 3;
        int k = 32 + j;
        int ch = (m >> 2) + 16 * mtc + 4 * (m & 3);
        const float* wsrc = cv ? wrc : wrh;
        if (ch < 40) val = wsrc[(ch * 40 + k) * 3 + dx];
    }
    wsA[i] = (__bf16)val;
}

// ---------------------------------------------------------------------------
// is_ws layout: [b][t][mt][gate][wv][q*16+l16]  (float)
//   flat = (b*64+t)*10240 + mt*1024 + gate*256 + wv*64 + q*16 + l16
__global__ __launch_bounds__(256) void conv7_kernel(
        const float* __restrict__ inp, const float* __restrict__ tgt,
        const float* __restrict__ w_is, const float* __restrict__ b_is,
        const float* __restrict__ w_cis, const float* __restrict__ b_cis,
        float* __restrict__ is_ws) {
    int b = blockIdx.x >> 6, y = blockIdx.x & 63;
    int w = threadIdx.x & 63, qg = threadIdx.x >> 6;
    const float* sb = ((qg < 2) ? inp : tgt) + b * 4096;
    float patch[7][7];
#pragma unroll
    for (int dy = 0; dy < 7; dy++) {
        int yy = y + dy - 3;
#pragma unroll
        for (int dx = 0; dx < 7; dx++) {
            int xx = w + dx - 3;
            patch[dy][dx] = (yy >= 0 && yy < 64 && xx >= 0 && xx < 64)
                                ? sb[yy * 64 + xx] : 0.0f;
        }
    }
    size_t base = (size_t)(b * 64 + y) * 10240 + (w >> 4) * 64 + (w & 15);
    if (qg < 2) {
        for (int mm = 0; mm < 40; mm++) {
            int o = qg * 40 + mm;             // combined ch 0..79
            float acc = b_cis[o];
            const float* wp = w_cis + o * 49;
#pragma unroll
            for (int dy = 0; dy < 7; dy++)
#pragma unroll
                for (int dx = 0; dx < 7; dx++)
                    acc += wp[dy * 7 + dx] * patch[dy][dx];
            int gate = o / 40, cc = o % 40;
            is_ws[base + (cc >> 2) * 1024 + gate * 256 + (cc & 3) * 16] = acc;
        }
    } else {
        for (int mm = 0; mm < 40; mm++) {
            int oc = (qg - 2) * 40 + mm;      // 0..79
            int o = 80 + oc;                  // combined ch 80..159
            float acc = b_is[oc];
            const float* wp = w_is + oc * 49;
            // mask A: rows 0..2 full, row 3 cols 0..2, center excluded
#pragma unroll
            for (int dy = 0; dy < 3; dy++)
#pragma unroll
                for (int dx = 0; dx < 7; dx++)
                    acc += wp[dy * 7 + dx] * patch[dy][dx];
#pragma unroll
            for (int dx = 0; dx < 3; dx++)
                acc += wp[3 * 7 + dx] * patch[3][dx];
            int gate = o / 40, cc = o % 40;
            is_ws[base + (cc >> 2) * 1024 + gate * 256 + (cc & 3) * 16] = acc;
        }
    }
}

// ---------------------------------------------------------------------------
__global__ __launch_bounds__(256, 1) void rnn_kernel(
        const float* __restrict__ is_ws, const __bf16* __restrict__ wsA,
        const float* __restrict__ b_rh, const float* __restrict__ b_rc,
        const float* __restrict__ b_cell, float* __restrict__ hid_ws) {
    // conv A-frags: ks0 9216 bf16 + ks1 2304 bf16
    __shared__ __align__(16) __bf16 aconv[9216 + 2304];
    // state, transposed [n 0..65][ch 0..55], 4 buffers: hA,cA,hB,cB
    __shared__ __align__(16) __bf16 stT[4][66 * ST_STRIDE];
    __shared__ float bc_l[7 * 40 * 4];     // [l][cc][gate]
    __shared__ float br_p[2 * 3 * 4 * 4];  // [cv][mtc][q][r], ch=q+16mtc+4r

    const __bf16* wA_c0 = wsA;             // 70*512
    const __bf16* wA_c1 = wsA + 35840;     // 70*128
    const __bf16* gconv = wsA + 44800;     // 11520

    const int tid = threadIdx.x, b = blockIdx.x;
    const int wv = tid >> 6, lane = tid & 63;
    const int q = lane >> 4, l16 = lane & 15;
    const int w = wv * 16 + l16;

    // ---- one-time init ----
    for (int i = tid; i < 11520 / 8; i += 256)
        ((f32x4*)aconv)[i] = ((const f32x4*)gconv)[i];
    for (int i = tid; i < 4 * 66 * ST_STRIDE / 8; i += 256)
        ((f32x4*)stT)[i] = f32x4{0.f, 0.f, 0.f, 0.f};
    for (int i = tid; i < 1120; i += 256) {
        int l = i / 160, rm = i % 160, g = rm / 40, cc = rm % 40;
        bc_l[(l * 40 + cc) * 4 + g] = b_cell[i];
    }
    for (int i = tid; i < 96; i += 256) {
        int r = i & 3, qq = (i >> 2) & 3, mtc = (i >> 4) % 3, cv = i / 48;
        int ch = qq + 16 * mtc + 4 * r;
        br_p[i] = (ch < 40) ? (cv ? b_rc[ch] : b_rh[ch]) : 0.0f;
    }
    __syncthreads();

    bf16x8 zf;
#pragma unroll
    for (int j = 0; j < 8; j++) zf[j] = (__bf16)0.0f;

    float c_reg[10];
    float xv[10][4];
    int cur = 0;   // hC=stT[cur], cC=stT[cur+1], hN=stT[2-cur], cN=stT[3-cur]

    for (int t = 0; t < 64; t++) {
        const __bf16* hC = stT[cur];
        const __bf16* cC = stT[cur + 1];
        __bf16* hN = stT[2 - cur];
        __bf16* cN = stT[3 - cur];

        // ---- x preload (coalesced 256B per (mt,gate)) ----
        const size_t xbase = (size_t)(b * 64 + t) * 10240 + wv * 64 + lane;
#pragma unroll
        for (int mt = 0; mt < 10; mt++)
#pragma unroll
            for (int r = 0; r < 4; r++)
                xv[mt][r] = is_ws[xbase + mt * 1024 + r * 256];

        // ---- phase A: 1x3 convs as 3 dx-shifted K=40 GEMMs ----
        f32x4 ah[3], ac[3];
#pragma unroll
        for (int m3 = 0; m3 < 3; m3++) {
            ah[m3] = f32x4{0.f, 0.f, 0.f, 0.f};
            ac[m3] = f32x4{0.f, 0.f, 0.f, 0.f};
        }
#pragma unroll
        for (int dx = 0; dx < 3; dx++) {
            int row = w + dx;              // 0..65 (includes neighbor halos)
#pragma unroll
            for (int ks = 0; ks < 2; ks++) {
                int col = ks ? (q == 0 ? 32 : 40) : q * 8;
                bf16x8 bh = *(const bf16x8*)&hC[row * ST_STRIDE + col];
                bf16x8 bc2 = *(const bf16x8*)&cC[row * ST_STRIDE + col];
#pragma unroll
                for (int mtc = 0; mtc < 3; mtc++) {
                    int ih = (0 * 3 + dx) * 3 + mtc;
                    int ic = (3 + dx) * 3 + mtc;
                    bf16x8 afh, afc;
                    if (ks == 0) {
                        afh = *(const bf16x8*)&aconv[(ih * 64 + lane) * 8];
                        afc = *(const bf16x8*)&aconv[(ic * 64 + lane) * 8];
                    } else if (q == 0) {
                        afh = *(const bf16x8*)&aconv[9216 + (ih * 16 + l16) * 8];
                        afc = *(const bf16x8*)&aconv[9216 + (ic * 16 + l16) * 8];
                    } else {
                        afh = zf;
                        afc = zf;
                    }
                    ah[mtc] = __builtin_amdgcn_mfma_f32_16x16x32_bf16(
                        afh, bh, ah[mtc], 0, 0, 0);
                    ac[mtc] = __builtin_amdgcn_mfma_f32_16x16x32_bf16(
                        afc, bc2, ac[mtc], 0, 0, 0);
                }
            }
        }
        // D layout: lane (q,l16) holds rows m=q*4+r of tile mtc, col l16.
        // ch = q + 16*mtc + 4*r ; phase-B mt = 4*mtc + r (valid < 10).
#pragma unroll
        for (int mtc = 0; mtc < 3; mtc++) {
            f32x4 bh4 = *(const f32x4*)&br_p[((0 + mtc) * 4 + q) * 4];
            f32x4 bc4 = *(const f32x4*)&br_p[((3 + mtc) * 4 + q) * 4];
#pragma unroll
            for (int r = 0; r < 4; r++) {
                int mt = 4 * mtc + r;
                if (mt < 10) {
                    int ch = q + 16 * mtc + 4 * r;
                    c_reg[mt] = ac[mtc][r] + bc4[r];
                    hN[(w + 1) * ST_STRIDE + ch] =
                        (__bf16)(ah[mtc][r] + bh4[r]);
                }
            }
        }

        // ---- phase B: 7 layers, barrier-free (wave-synchronous LDS) ----
        for (int l = 0; l < 7; l++) {
            bf16x8 b0 = *(const bf16x8*)&hN[(w + 1) * ST_STRIDE + q * 8];
            bf16x8 b1 = *(const bf16x8*)
                &hN[(w + 1) * ST_STRIDE + (q == 0 ? 32 : 40)];
#pragma unroll
            for (int mt = 0; mt < 10; mt++) {
                bf16x8 a0 = *(const bf16x8*)&wA_c0[((l * 10 + mt) * 64 + lane) * 8];
                bf16x8 a1 = (q == 0)
                    ? *(const bf16x8*)&wA_c1[((l * 10 + mt) * 16 + l16) * 8]
                    : zf;
                f32x4 acc = __builtin_amdgcn_mfma_f32_16x16x32_bf16(
                    a0, b0, f32x4{0.f, 0.f, 0.f, 0.f}, 0, 0, 0);
                acc = __builtin_amdgcn_mfma_f32_16x16x32_bf16(
                    a1, b1, acc, 0, 0, 0);
                f32x4 bcv = *(const f32x4*)&bc_l[(l * 40 + 4 * mt + q) * 4];
                float vi = acc[0] + xv[mt][0] + bcv[0];
                float vf = acc[1] + xv[mt][1] + bcv[1];
                float vo = acc[2] + xv[mt][2] + bcv[2];
                float vg = acc[3] + xv[mt][3] + bcv[3];
                // shared-rcp LSTM gates: 5 exp2 + 3 rcp per cell
                float Ei = __builtin_amdgcn_exp2f(fminf(-LOG2E * vi, 44.f));
                float Ef = __builtin_amdgcn_exp2f(fminf(-LOG2E * vf, 44.f));
                float Eo = __builtin_amdgcn_exp2f(fminf(-LOG2E * vo, 44.f));
                float Eg = __builtin_amdgcn_exp2f(
                    fminf(-2.0f * LOG2E * vg, 44.f));
                float f = __builtin_amdgcn_rcpf(1.0f + Ef);
                float ig = (1.0f - Eg) *
                    __builtin_amdgcn_rcpf((1.0f + Ei) * (1.0f + Eg));
                float c = __builtin_fmaf(f, c_reg[mt], ig);
                c_reg[mt] = c;
                float Ec = __builtin_amdgcn_exp2f(
                    fminf(-2.0f * LOG2E * c, 44.f));
                float h = (1.0f - Ec) *
                    __builtin_amdgcn_rcpf((1.0f + Eo) * (1.0f + Ec));
                hN[(w + 1) * ST_STRIDE + 4 * mt + q] = (__bf16)h;
                if (l == 6) {
                    cN[(w + 1) * ST_STRIDE + 4 * mt + q] = (__bf16)c;
                    hid_ws[(size_t)((b * 64 + t) * 40 + 4 * mt + q) * 64 + w] = h;
                }
            }
        }
        __syncthreads();
        cur ^= 2;
    }
}

// ---------------------------------------------------------------------------
__global__ __launch_bounds__(256) void out_kernel(
        const float* __restrict__ hid_ws, const float* __restrict__ w_out,
        const float* __restrict__ b_out, float* __restrict__ out) {
    __shared__ float wlds[40 * 264];   // transposed [k][o]
    __shared__ float hlds[40 * 64];
    int b = blockIdx.x >> 6, y = blockIdx.x & 63;
    int tid = threadIdx.x;
    for (int i = tid; i < 10240; i += 256) {
        int o = i / 40, k = i - o * 40;
        wlds[k * 264 + o] = w_out[i];
    }
    const float* hbp = hid_ws + (size_t)(b * 64 + y) * 40 * 64;
    for (int i = tid; i < 2560; i += 256) hlds[i] = hbp[i];
    __syncthreads();

    int tn = tid & 7, tm = tid >> 3;
    int wbase = tn * 8, obase = tm * 8;
    float acc[8][8];
#pragma unroll
    for (int io = 0; io < 8; io++)
#pragma unroll
        for (int iw = 0; iw < 8; iw++) acc[io][iw] = 0.0f;

    for (int k = 0; k < 40; k++) {
        f32x4 hA = *(const f32x4*)&hlds[k * 64 + wbase];
        f32x4 hB = *(const f32x4*)&hlds[k * 64 + wbase + 4];
        f32x4 wA = *(const f32x4*)&wlds[k * 264 + obase];
        f32x4 wB = *(const f32x4*)&wlds[k * 264 + obase + 4];
#pragma unroll
        for (int io = 0; io < 8; io++) {
            float wo = (io < 4) ? wA[io] : wB[io - 4];
#pragma unroll
            for (int iw = 0; iw < 8; iw++) {
                float hx = (iw < 4) ? hA[iw] : hB[iw - 4];
                acc[io][iw] = __builtin_fmaf(wo, hx, acc[io][iw]);
            }
        }
    }
#pragma unroll
    for (int io = 0; io < 8; io++) {
        int o = obase + io;
        float bo = b_out[o];
        f32x4 s0, s1;
#pragma unroll
        for (int iw = 0; iw < 4; iw++)
            s0[iw] = fmaxf(acc[io][iw] + bo, 0.0f);
#pragma unroll
        for (int iw = 0; iw < 4; iw++)
            s1[iw] = fmaxf(acc[io][iw + 4] + bo, 0.0f);
        float* ob = out + (size_t)((b * 256 + o) * 64 + y) * 64 + wbase;
        *(f32x4*)ob = s0;
        *(f32x4*)(ob + 4) = s1;
    }
}

// ---------------------------------------------------------------------------
extern "C" void kernel_launch(void* const* d_in, const int* in_sizes, int n_in,
                              void* d_out, int out_size, void* d_ws,
                              size_t ws_size, hipStream_t stream) {
    const float* input  = (const float*)d_in[0];
    const float* target = (const float*)d_in[1];
    const float* w_is   = (const float*)d_in[2];
    const float* b_is   = (const float*)d_in[3];
    const float* w_cis  = (const float*)d_in[4];
    const float* b_cis  = (const float*)d_in[5];
    const float* w_rh   = (const float*)d_in[6];
    const float* b_rh   = (const float*)d_in[7];
    const float* w_rc   = (const float*)d_in[8];
    const float* b_rc   = (const float*)d_in[9];
    const float* w_cell = (const float*)d_in[10];
    const float* b_cell = (const float*)d_in[11];
    const float* w_out  = (const float*)d_in[12];
    const float* b_out  = (const float*)d_in[13];
    float* out = (float*)d_out;

    char* ws = (char*)d_ws;
    float*  is_ws  = (float*)ws;                    // 41,943,040 B
    float*  hid_ws = (float*)(ws + 41943040);       // 10,485,760 B
    __bf16* wsA    = (__bf16*)(ws + 52428800);      //    112,640 B

    prep_kernel<<<220, 256, 0, stream>>>(w_cell, w_rh, w_rc, wsA);
    conv7_kernel<<<1024, 256, 0, stream>>>(input, target, w_is, b_is, w_cis,
                                           b_cis, is_ws);
    rnn_kernel<<<16, 256, 0, stream>>>(is_ws, wsA, b_rh, b_rc, b_cell, hid_ws);
    out_kernel<<<1024, 256, 0, stream>>>(hid_ws, w_out, b_out, out);
}

// Round 3
// 658.925 us; speedup vs baseline: 2.1977x; 2.1977x over previous
//
#include <hip/hip_runtime.h>

// ---------------------------------------------------------------------------
// RowLSTM on MI355X — round 3: 4-way column split per batch (64 CUs active),
// round-1-style 10-wave blocks (1 cell/lane/layer), cross-block halo exchange
// via agent-scope atomics with per-row flags (parity double-buffered).
// ---------------------------------------------------------------------------

typedef __bf16 bf16x8 __attribute__((ext_vector_type(8)));
typedef __bf16 bf16x4 __attribute__((ext_vector_type(4)));
typedef float  f32x4  __attribute__((ext_vector_type(4)));

#define LOG2E 1.442695040889f

// ---------------------------------------------------------------------------
// wsA global layout (bf16):
//   [0     ,35840) cell ks0 : [(l*10+mt)][lane][j]  row=(m&3)*40+4*mt+(m>>2)
//   [35840 ,44800) cell ks1 : [(l*10+mt)][m   ][j]  (k=32+j)
//   [44800 ,54016) conv ks0 : [((cv*3+dx)*3+mtc)][lane][j]  ch=mtc*16+m
//   [54016 ,56320) conv ks1 : [((cv*3+dx)*3+mtc)][m   ][j]
__global__ __launch_bounds__(256) void prep_kernel(
        const float* __restrict__ wcell, const float* __restrict__ wrh,
        const float* __restrict__ wrc, __bf16* __restrict__ wsA) {
    int i = blockIdx.x * 256 + threadIdx.x;
    if (i >= 56320) return;
    float val = 0.0f;
    if (i < 35840) {                       // cell ks0
        int j = i & 7, lane = (i >> 3) & 63, lm = i >> 9;
        int mt = lm % 10, l = lm / 10;
        int k = (lane >> 4) * 8 + j, m = lane & 15;
        int row = (m & 3) * 40 + 4 * mt + (m >> 2);  // gate*40 + cc
        val = wcell[(l * 160 + row) * 40 + k];
    } else if (i < 44800) {                // cell ks1
        int i2 = i - 35840;
        int j = i2 & 7, m = (i2 >> 3) & 15, lm = i2 >> 7;
        int mt = lm % 10, l = lm / 10;
        int k = 32 + j;
        int row = (m & 3) * 40 + 4 * mt + (m >> 2);
        val = wcell[(l * 160 + row) * 40 + k];
    } else if (i < 54016) {                // conv ks0 (identity ch mapping)
        int i3 = i - 44800;
        int j = i3 & 7, lane = (i3 >> 3) & 63, idx = i3 >> 9;  // 0..17
        int mtc = idx % 3, t2 = idx / 3, dx = t2 % 3, cv = t2 / 3;
        int k = (lane >> 4) * 8 + j, m = lane & 15;
        int ch = mtc * 16 + m;
        const float* wsrc = cv ? wrc : wrh;    // [40][40][1][3]
        if (ch < 40) val = wsrc[(ch * 40 + k) * 3 + dx];
    } else {                               // conv ks1
        int i4 = i - 54016;
        int j = i4 & 7, m = (i4 >> 3) & 15, idx = i4 >> 7;
        int mtc = idx % 3, t2 = idx / 3, dx = t2 % 3, cv = t2 / 3;
        int k = 32 + j;
        int ch = mtc * 16 + m;
        const float* wsrc = cv ? wrc : wrh;
        if (ch < 40) val = wsrc[(ch * 40 + k) * 3 + dx];
    }
    wsA[i] = (__bf16)val;
}

// ---------------------------------------------------------------------------
// x_ws layout (float): [b][t][g4][wv10][q4][l16][gate4]
//   flat = ((((b*64+t)*4+g)*10+wv)*4+q)*64 + l16*4 + gate
// Thread (qq=tid>>6, w=tid&63) computes all 4 gates of cc=4j+qq for col w:
//   gate0 = conv_cis row cc, gate1 = row 40+cc (input patch)
//   gate2 = masked conv row cc, gate3 = row 40+cc (target patch)
__global__ __launch_bounds__(256) void conv7_kernel(
        const float* __restrict__ inp, const float* __restrict__ tgt,
        const float* __restrict__ w_is, const float* __restrict__ b_is,
        const float* __restrict__ w_cis, const float* __restrict__ b_cis,
        float* __restrict__ x_ws) {
    int b = blockIdx.x >> 6, y = blockIdx.x & 63;
    int tid = threadIdx.x, qq = tid >> 6, w = tid & 63;
    const float* ib = inp + b * 4096;
    const float* tb = tgt + b * 4096;
    float pin[7][7], ptg[4][7];
#pragma unroll
    for (int dy = 0; dy < 7; dy++) {
        int yy = y + dy - 3;
#pragma unroll
        for (int dx = 0; dx < 7; dx++) {
            int xx = w + dx - 3;
            bool ok = (yy >= 0 && yy < 64 && xx >= 0 && xx < 64);
            pin[dy][dx] = ok ? ib[yy * 64 + xx] : 0.0f;
            if (dy < 4) ptg[dy][dx] = ok ? tb[yy * 64 + xx] : 0.0f;
        }
    }
    int g = w >> 4, l16 = w & 15;
    for (int j = 0; j < 10; j++) {
        int cc = 4 * j + qq;
        float a0 = b_cis[cc], a1 = b_cis[40 + cc];
        float a2 = b_is[cc], a3 = b_is[40 + cc];
        const float* w0 = w_cis + cc * 49;
        const float* w1 = w_cis + (40 + cc) * 49;
        const float* w2 = w_is + cc * 49;
        const float* w3 = w_is + (40 + cc) * 49;
#pragma unroll
        for (int dy = 0; dy < 7; dy++)
#pragma unroll
            for (int dx = 0; dx < 7; dx++) {
                a0 = __builtin_fmaf(w0[dy * 7 + dx], pin[dy][dx], a0);
                a1 = __builtin_fmaf(w1[dy * 7 + dx], pin[dy][dx], a1);
            }
        // mask A: rows 0..2 full, row 3 cols 0..2
#pragma unroll
        for (int dy = 0; dy < 3; dy++)
#pragma unroll
            for (int dx = 0; dx < 7; dx++) {
                a2 = __builtin_fmaf(w2[dy * 7 + dx], ptg[dy][dx], a2);
                a3 = __builtin_fmaf(w3[dy * 7 + dx], ptg[dy][dx], a3);
            }
#pragma unroll
        for (int dx = 0; dx < 3; dx++) {
            a2 = __builtin_fmaf(w2[21 + dx], ptg[3][dx], a2);
            a3 = __builtin_fmaf(w3[21 + dx], ptg[3][dx], a3);
        }
        size_t idx = (size_t)((((b * 64 + y) * 4 + g) * 10 + j) * 4 + qq) * 64
                     + l16 * 4;
        *(f32x4*)&x_ws[idx] = f32x4{a0, a1, a2, a3};
    }
}

// ---------------------------------------------------------------------------
// rnn: 64 blocks (b,g) x 640 threads (10 waves). Block owns 16 cols
// [16g,16g+16). Wave wv = M-tile wv of the 160x40 cell GEMM; lane (q,l16)
// owns cell channel cc=4wv+q, col l16 -> acc regs = (i,f,o,g).
__global__ __launch_bounds__(640, 1) void rnn_kernel(
        const float* __restrict__ x_ws, const __bf16* __restrict__ wsA,
        const float* __restrict__ b_rh, const float* __restrict__ b_rc,
        const float* __restrict__ b_cell, float* __restrict__ hid_ws,
        unsigned* __restrict__ halo_ws, unsigned* __restrict__ flags) {
    __shared__ __align__(16) __bf16 aconv0[9216];
    __shared__ __align__(16) __bf16 aconv1[2304];
    __shared__ __align__(16) __bf16 acell1[8960];
    // transposed state [sc 0..17][ch 0..55], sc0 = left halo, 17 = right
    __shared__ __align__(16) __bf16 hC[18 * 56];
    __shared__ __align__(16) __bf16 cC[18 * 56];
    __shared__ __align__(16) __bf16 hL[2][16 * 56];  // layer double-buffer
    __shared__ float cwf[40 * 16];       // conv c' fp32 [ch][col]
    __shared__ float bc_l[7 * 40 * 4];   // [l][cc][gate]
    __shared__ float brp[2][48];         // conv bias h/c, padded

    const int bid = blockIdx.x, g = bid & 3, b = bid >> 2;
    const int tid = threadIdx.x, wv = tid >> 6, lane = tid & 63;
    const int q = lane >> 4, l16 = lane & 15, cc = 4 * wv + q;
    const int W0 = g * 16;

    const __bf16* g_acell0 = wsA;
    const __bf16* g_acell1 = wsA + 35840;
    const __bf16* g_aconv0 = wsA + 44800;
    const __bf16* g_aconv1 = wsA + 54016;

    for (int i = tid; i < 1152; i += 640)
        ((f32x4*)aconv0)[i] = ((const f32x4*)g_aconv0)[i];
    for (int i = tid; i < 288; i += 640)
        ((f32x4*)aconv1)[i] = ((const f32x4*)g_aconv1)[i];
    for (int i = tid; i < 1120; i += 640)
        ((f32x4*)acell1)[i] = ((const f32x4*)g_acell1)[i];
    for (int i = tid; i < 126; i += 640) {
        ((f32x4*)hC)[i] = f32x4{0.f, 0.f, 0.f, 0.f};
        ((f32x4*)cC)[i] = f32x4{0.f, 0.f, 0.f, 0.f};
    }
    for (int i = tid; i < 224; i += 640)
        ((f32x4*)hL)[i] = f32x4{0.f, 0.f, 0.f, 0.f};
    for (int i = tid; i < 1120; i += 640) {
        int l = i / 160, rm = i % 160, gg = rm / 40, c2 = rm % 40;
        bc_l[(l * 40 + c2) * 4 + gg] = b_cell[i];
    }
    for (int i = tid; i < 96; i += 640) {
        int cv = i / 48, ch = i % 48;
        brp[cv][ch] = (ch < 40) ? (cv ? b_rc[ch] : b_rh[ch]) : 0.0f;
    }
    __syncthreads();

    bf16x8 zf;
#pragma unroll
    for (int j = 0; j < 8; j++) zf[j] = (__bf16)0.0f;

    for (int t = 0; t < 64; t++) {
        // ---- x load (coalesced f32x4/lane) ----
        f32x4 xv = *(const f32x4*)&x_ws[
            (size_t)((((b * 64 + t) * 4 + g) * 10 + wv) * 4 + q) * 64
            + l16 * 4];

        // ---- phase A: 1x3 convs (waves 0..5), 3 dx-shifted K=40 GEMMs ----
        if (wv < 6) {
            int cv = wv / 3, mtc = wv % 3;
            const __bf16* st = cv ? cC : hC;
            f32x4 acc = f32x4{0.f, 0.f, 0.f, 0.f};
#pragma unroll
            for (int dx = 0; dx < 3; dx++) {
                int rowb = (l16 + dx) * 56;
#pragma unroll
                for (int ks = 0; ks < 2; ks++) {
                    bf16x8 bb = *(const bf16x8*)
                        &st[rowb + (ks ? (q == 0 ? 32 : 40) : q * 8)];
                    int it = (cv * 3 + dx) * 3 + mtc;
                    bf16x8 af;
                    if (ks == 0)
                        af = *(const bf16x8*)&aconv0[(it * 64 + lane) * 8];
                    else if (q == 0)
                        af = *(const bf16x8*)&aconv1[(it * 16 + l16) * 8];
                    else
                        af = zf;
                    acc = __builtin_amdgcn_mfma_f32_16x16x32_bf16(
                        af, bb, acc, 0, 0, 0);
                }
            }
            f32x4 bias4 = *(const f32x4*)&brp[cv][mtc * 16 + q * 4];
            if (cv == 0) {
                if (mtc < 2 || q < 2) {   // ch = mtc*16+q*4+r < 40
                    bf16x4 hv;
#pragma unroll
                    for (int r = 0; r < 4; r++)
                        hv[r] = (__bf16)(acc[r] + bias4[r]);
                    *(bf16x4*)&hL[0][l16 * 56 + mtc * 16 + q * 4] = hv;
                }
            } else {
#pragma unroll
                for (int r = 0; r < 4; r++) {
                    int ch = mtc * 16 + q * 4 + r;
                    if (ch < 40) cwf[ch * 16 + l16] = acc[r] + bias4[r];
                }
            }
        }
        __syncthreads();

        // ---- 7 layers ----
        float c_reg = 0.0f;
        for (int l = 0; l < 7; l++) {
            const __bf16* hb = hL[l & 1];
            bf16x8 b0 = *(const bf16x8*)&hb[l16 * 56 + q * 8];
            bf16x8 b1 = *(const bf16x8*)&hb[l16 * 56 + (q == 0 ? 32 : 40)];
            bf16x8 a0 = *(const bf16x8*)
                &g_acell0[((l * 10 + wv) * 64 + lane) * 8];
            bf16x8 a1 = (q == 0)
                ? *(const bf16x8*)&acell1[((l * 10 + wv) * 16 + l16) * 8]
                : zf;
            f32x4 acc = __builtin_amdgcn_mfma_f32_16x16x32_bf16(
                a0, b0, f32x4{0.f, 0.f, 0.f, 0.f}, 0, 0, 0);
            acc = __builtin_amdgcn_mfma_f32_16x16x32_bf16(a1, b1, acc, 0, 0, 0);
            f32x4 bcv = *(const f32x4*)&bc_l[(l * 40 + cc) * 4];
            if (l == 0) c_reg = cwf[cc * 16 + l16];
            float vi = acc[0] + xv[0] + bcv[0];
            float vf = acc[1] + xv[1] + bcv[1];
            float vo = acc[2] + xv[2] + bcv[2];
            float vg = acc[3] + xv[3] + bcv[3];
            float Ei = __builtin_amdgcn_exp2f(fminf(-LOG2E * vi, 44.f));
            float Ef = __builtin_amdgcn_exp2f(fminf(-LOG2E * vf, 44.f));
            float Eo = __builtin_amdgcn_exp2f(fminf(-LOG2E * vo, 44.f));
            float Eg = __builtin_amdgcn_exp2f(fminf(-2.f * LOG2E * vg, 44.f));
            float f = __builtin_amdgcn_rcpf(1.0f + Ef);
            float ig = (1.0f - Eg) *
                __builtin_amdgcn_rcpf((1.0f + Ei) * (1.0f + Eg));
            float c = __builtin_fmaf(f, c_reg, ig);
            c_reg = c;
            float Ec = __builtin_amdgcn_exp2f(fminf(-2.f * LOG2E * c, 44.f));
            float h = (1.0f - Ec) *
                __builtin_amdgcn_rcpf((1.0f + Eo) * (1.0f + Ec));
            if (l < 6) {
                hL[(l + 1) & 1][l16 * 56 + cc] = (__bf16)h;
            } else {
                hC[(1 + l16) * 56 + cc] = (__bf16)h;
                cC[(1 + l16) * 56 + cc] = (__bf16)c;
                hid_ws[(size_t)((b * 64 + t) * 40 + cc) * 64 + W0 + l16] = h;
                unsigned short hb16 =
                    __builtin_bit_cast(unsigned short, (__bf16)h);
                unsigned short cb16 =
                    __builtin_bit_cast(unsigned short, (__bf16)c);
                unsigned pk = (unsigned)hb16 | ((unsigned)cb16 << 16);
                if (l16 == 0 && g > 0)
                    __hip_atomic_store(
                        &halo_ws[((bid * 2 + 0) * 2 + (t & 1)) * 40 + cc], pk,
                        __ATOMIC_RELAXED, __HIP_MEMORY_SCOPE_AGENT);
                if (l16 == 15 && g < 3)
                    __hip_atomic_store(
                        &halo_ws[((bid * 2 + 1) * 2 + (t & 1)) * 40 + cc], pk,
                        __ATOMIC_RELAXED, __HIP_MEMORY_SCOPE_AGENT);
            }
            __syncthreads();
        }

        // ---- publish flag; prefetch neighbor halos for row t+1 ----
        if (tid == 0) {
            __threadfence();
            __hip_atomic_store(&flags[bid], (unsigned)(t + 1),
                               __ATOMIC_RELEASE, __HIP_MEMORY_SCOPE_AGENT);
        }
        if (t < 63) {
            const unsigned want = (unsigned)(t + 1);
            if (wv == 0 && g > 0 && lane < 40) {
                unsigned f = __hip_atomic_load(&flags[bid - 1],
                    __ATOMIC_ACQUIRE, __HIP_MEMORY_SCOPE_AGENT);
                while (f - want > 1u) {
                    __builtin_amdgcn_s_sleep(2);
                    f = __hip_atomic_load(&flags[bid - 1],
                        __ATOMIC_ACQUIRE, __HIP_MEMORY_SCOPE_AGENT);
                }
                unsigned u = __hip_atomic_load(
                    &halo_ws[(((bid - 1) * 2 + 1) * 2 + (t & 1)) * 40 + lane],
                    __ATOMIC_RELAXED, __HIP_MEMORY_SCOPE_AGENT);
                hC[lane] = __builtin_bit_cast(__bf16, (unsigned short)(u & 0xffffu));
                cC[lane] = __builtin_bit_cast(__bf16, (unsigned short)(u >> 16));
            }
            if (wv == 1 && g < 3 && lane < 40) {
                unsigned f = __hip_atomic_load(&flags[bid + 1],
                    __ATOMIC_ACQUIRE, __HIP_MEMORY_SCOPE_AGENT);
                while (f - want > 1u) {
                    __builtin_amdgcn_s_sleep(2);
                    f = __hip_atomic_load(&flags[bid + 1],
                        __ATOMIC_ACQUIRE, __HIP_MEMORY_SCOPE_AGENT);
                }
                unsigned u = __hip_atomic_load(
                    &halo_ws[(((bid + 1) * 2 + 0) * 2 + (t & 1)) * 40 + lane],
                    __ATOMIC_RELAXED, __HIP_MEMORY_SCOPE_AGENT);
                hC[17 * 56 + lane] =
                    __builtin_bit_cast(__bf16, (unsigned short)(u & 0xffffu));
                cC[17 * 56 + lane] =
                    __builtin_bit_cast(__bf16, (unsigned short)(u >> 16));
            }
        }
        __syncthreads();
    }
}

// ---------------------------------------------------------------------------
__global__ __launch_bounds__(256) void out_kernel(
        const float* __restrict__ hid_ws, const float* __restrict__ w_out,
        const float* __restrict__ b_out, float* __restrict__ out) {
    __shared__ float wlds[40 * 264];   // transposed [k][o]
    __shared__ float hlds[40 * 64];
    int b = blockIdx.x >> 6, y = blockIdx.x & 63;
    int tid = threadIdx.x;
    for (int i = tid; i < 10240; i += 256) {
        int o = i / 40, k = i - o * 40;
        wlds[k * 264 + o] = w_out[i];
    }
    const float* hbp = hid_ws + (size_t)(b * 64 + y) * 40 * 64;
    for (int i = tid; i < 2560; i += 256) hlds[i] = hbp[i];
    __syncthreads();

    int tn = tid & 7, tm = tid >> 3;
    int wbase = tn * 8, obase = tm * 8;
    float acc[8][8];
#pragma unroll
    for (int io = 0; io < 8; io++)
#pragma unroll
        for (int iw = 0; iw < 8; iw++) acc[io][iw] = 0.0f;

    for (int k = 0; k < 40; k++) {
        f32x4 hA = *(const f32x4*)&hlds[k * 64 + wbase];
        f32x4 hB = *(const f32x4*)&hlds[k * 64 + wbase + 4];
        f32x4 wA = *(const f32x4*)&wlds[k * 264 + obase];
        f32x4 wB = *(const f32x4*)&wlds[k * 264 + obase + 4];
#pragma unroll
        for (int io = 0; io < 8; io++) {
            float wo = (io < 4) ? wA[io] : wB[io - 4];
#pragma unroll
            for (int iw = 0; iw < 8; iw++) {
                float hx = (iw < 4) ? hA[iw] : hB[iw - 4];
                acc[io][iw] = __builtin_fmaf(wo, hx, acc[io][iw]);
            }
        }
    }
#pragma unroll
    for (int io = 0; io < 8; io++) {
        int o = obase + io;
        float bo = b_out[o];
        f32x4 s0, s1;
#pragma unroll
        for (int iw = 0; iw < 4; iw++)
            s0[iw] = fmaxf(acc[io][iw] + bo, 0.0f);
#pragma unroll
        for (int iw = 0; iw < 4; iw++)
            s1[iw] = fmaxf(acc[io][iw + 4] + bo, 0.0f);
        float* ob = out + (size_t)((b * 256 + o) * 64 + y) * 64 + wbase;
        *(f32x4*)ob = s0;
        *(f32x4*)(ob + 4) = s1;
    }
}

// ---------------------------------------------------------------------------
extern "C" void kernel_launch(void* const* d_in, const int* in_sizes, int n_in,
                              void* d_out, int out_size, void* d_ws,
                              size_t ws_size, hipStream_t stream) {
    const float* input  = (const float*)d_in[0];
    const float* target = (const float*)d_in[1];
    const float* w_is   = (const float*)d_in[2];
    const float* b_is   = (const float*)d_in[3];
    const float* w_cis  = (const float*)d_in[4];
    const float* b_cis  = (const float*)d_in[5];
    const float* w_rh   = (const float*)d_in[6];
    const float* b_rh   = (const float*)d_in[7];
    const float* w_rc   = (const float*)d_in[8];
    const float* b_rc   = (const float*)d_in[9];
    const float* w_cell = (const float*)d_in[10];
    const float* b_cell = (const float*)d_in[11];
    const float* w_out  = (const float*)d_in[12];
    const float* b_out  = (const float*)d_in[13];
    float* out = (float*)d_out;

    char* ws = (char*)d_ws;
    float*    x_ws    = (float*)ws;                     // 41,943,040 B
    float*    hid_ws  = (float*)(ws + 41943040);        // 10,485,760 B
    __bf16*   wsA     = (__bf16*)(ws + 52428800);       //    112,640 B
    unsigned* halo_ws = (unsigned*)(ws + 52541440);     //     40,960 B
    unsigned* flags   = (unsigned*)(ws + 52582400);     //        256 B

    prep_kernel<<<220, 256, 0, stream>>>(w_cell, w_rh, w_rc, wsA);
    conv7_kernel<<<1024, 256, 0, stream>>>(input, target, w_is, b_is, w_cis,
                                           b_cis, x_ws);
    rnn_kernel<<<64, 640, 0, stream>>>(x_ws, wsA, b_rh, b_rc, b_cell, hid_ws,
                                       halo_ws, flags);
    out_kernel<<<1024, 256, 0, stream>>>(hid_ws, w_out, b_out, out);
}

// Round 5
// 631.413 us; speedup vs baseline: 2.2935x; 1.0436x over previous
//
#include <hip/hip_runtime.h>

// ---------------------------------------------------------------------------
// RowLSTM on MI355X — round 5: round-4 critical-path design with the LDS
// init bug fixed (correct extents, barrier-separated constant-channel init).
//  - A-fragments (cell + conv) in REGISTERS (no global loads in layer chain).
//  - Biases folded into the GEMM via constant channel h[40]=1 (bias at k=40
//    in the extended a1 fragment; conv bias only in the dx==1 fragment).
//  - Cell weights/x pre-scaled by -log2e (-2log2e for g-gate) -> MFMA output
//    feeds exp2 directly.
//  - lgkm-only barriers inside the row; full vmcnt drain only at l==6.
// Structure: 64 blocks (b,g) x 640 thr (10 waves); wave=M-tile, lane=1 cell;
// halo exchange via agent-scope atomics + parity flags (round-3 proven).
// ---------------------------------------------------------------------------

typedef __bf16 bf16x8 __attribute__((ext_vector_type(8)));
typedef __bf16 bf16x4 __attribute__((ext_vector_type(4)));
typedef float  f32x4  __attribute__((ext_vector_type(4)));

#define SC1 (-1.44269504089f)   // -log2(e)
#define SC2 (-2.88539008178f)   // -2 log2(e)

#define BARRIER_LGKM() __asm__ volatile("s_waitcnt lgkmcnt(0)\ns_barrier" ::: "memory")
#define BARRIER_ALL()  __asm__ volatile("s_waitcnt vmcnt(0) lgkmcnt(0)\ns_barrier" ::: "memory")

// ---------------------------------------------------------------------------
// wsA (bf16 elems):
//  [0     ,35840) cell a0 : [(l*10+mt)][lane][j]  k=q*8+j, row=r*40+4mt+(m>>2)
//                           scaled by (r==3 ? SC2 : SC1)
//  [35840 ,71680) cell a1x: [(l*10+mt)][lane][j]  k=32+q*8+j; k<40 weight,
//                           k==40 bias (b_cell), else 0; same scale
//  [71680 ,80896) conv a0 : [(cv*9+dx*3+mtc)][lane][j]  ch=16mtc+m (unscaled)
//  [80896 ,90112) conv a1x: same idx; k<40 weight, k==40&&dx==1 bias, else 0
__global__ __launch_bounds__(256) void prep_kernel(
        const float* __restrict__ wcell, const float* __restrict__ wrh,
        const float* __restrict__ wrc, const float* __restrict__ bcell,
        const float* __restrict__ brh, const float* __restrict__ brc,
        __bf16* __restrict__ wsA) {
    int i = blockIdx.x * 256 + threadIdx.x;
    if (i >= 90112) return;
    float val = 0.0f;
    if (i < 35840) {                       // cell a0
        int j = i & 7, lane = (i >> 3) & 63, lm = i >> 9;
        int mt = lm % 10, l = lm / 10;
        int k = (lane >> 4) * 8 + j, m = lane & 15, r = m & 3;
        int row = r * 40 + 4 * mt + (m >> 2);
        val = wcell[(l * 160 + row) * 40 + k] * (r == 3 ? SC2 : SC1);
    } else if (i < 71680) {                // cell a1 ext
        int i2 = i - 35840;
        int j = i2 & 7, lane = (i2 >> 3) & 63, lm = i2 >> 9;
        int mt = lm % 10, l = lm / 10;
        int k = 32 + (lane >> 4) * 8 + j, m = lane & 15, r = m & 3;
        int row = r * 40 + 4 * mt + (m >> 2);
        float s = (r == 3 ? SC2 : SC1);
        if (k < 40)       val = wcell[(l * 160 + row) * 40 + k] * s;
        else if (k == 40) val = bcell[l * 160 + row] * s;
    } else if (i < 80896) {                // conv a0
        int i3 = i - 71680;
        int j = i3 & 7, lane = (i3 >> 3) & 63, idx = i3 >> 9;   // 0..17
        int mtc = idx % 3, t2 = idx / 3, dx = t2 % 3, cv = t2 / 3;
        int k = (lane >> 4) * 8 + j;
        int ch = 16 * mtc + (lane & 15);
        const float* w = cv ? wrc : wrh;       // [40][40][1][3]
        if (ch < 40) val = w[(ch * 40 + k) * 3 + dx];
    } else {                               // conv a1 ext
        int i4 = i - 80896;
        int j = i4 & 7, lane = (i4 >> 3) & 63, idx = i4 >> 9;
        int mtc = idx % 3, t2 = idx / 3, dx = t2 % 3, cv = t2 / 3;
        int k = 32 + (lane >> 4) * 8 + j;
        int ch = 16 * mtc + (lane & 15);
        if (ch < 40) {
            const float* w = cv ? wrc : wrh;
            if (k < 40)                    val = w[(ch * 40 + k) * 3 + dx];
            else if (k == 40 && dx == 1)   val = (cv ? brc : brh)[ch];
        }
    }
    wsA[i] = (__bf16)val;
}

// ---------------------------------------------------------------------------
// x_ws (float, PRE-SCALED): [b][t][g4][mt10][q4][l16][gate4]
__global__ __launch_bounds__(256) void conv7_kernel(
        const float* __restrict__ inp, const float* __restrict__ tgt,
        const float* __restrict__ w_is, const float* __restrict__ b_is,
        const float* __restrict__ w_cis, const float* __restrict__ b_cis,
        float* __restrict__ x_ws) {
    int b = blockIdx.x >> 6, y = blockIdx.x & 63;
    int tid = threadIdx.x, qq = tid >> 6, w = tid & 63;
    const float* ib = inp + b * 4096;
    const float* tb = tgt + b * 4096;
    float pin[7][7], ptg[4][7];
#pragma unroll
    for (int dy = 0; dy < 7; dy++) {
        int yy = y + dy - 3;
#pragma unroll
        for (int dx = 0; dx < 7; dx++) {
            int xx = w + dx - 3;
            bool ok = (yy >= 0 && yy < 64 && xx >= 0 && xx < 64);
            pin[dy][dx] = ok ? ib[yy * 64 + xx] : 0.0f;
            if (dy < 4) ptg[dy][dx] = ok ? tb[yy * 64 + xx] : 0.0f;
        }
    }
    int g = w >> 4, l16 = w & 15;
    for (int j = 0; j < 10; j++) {
        int cc = 4 * j + qq;
        float a0 = b_cis[cc], a1 = b_cis[40 + cc];
        float a2 = b_is[cc], a3 = b_is[40 + cc];
        const float* w0 = w_cis + cc * 49;
        const float* w1 = w_cis + (40 + cc) * 49;
        const float* w2 = w_is + cc * 49;
        const float* w3 = w_is + (40 + cc) * 49;
#pragma unroll
        for (int dy = 0; dy < 7; dy++)
#pragma unroll
            for (int dx = 0; dx < 7; dx++) {
                a0 = __builtin_fmaf(w0[dy * 7 + dx], pin[dy][dx], a0);
                a1 = __builtin_fmaf(w1[dy * 7 + dx], pin[dy][dx], a1);
            }
#pragma unroll
        for (int dy = 0; dy < 3; dy++)
#pragma unroll
            for (int dx = 0; dx < 7; dx++) {
                a2 = __builtin_fmaf(w2[dy * 7 + dx], ptg[dy][dx], a2);
                a3 = __builtin_fmaf(w3[dy * 7 + dx], ptg[dy][dx], a3);
            }
#pragma unroll
        for (int dx = 0; dx < 3; dx++) {
            a2 = __builtin_fmaf(w2[21 + dx], ptg[3][dx], a2);
            a3 = __builtin_fmaf(w3[21 + dx], ptg[3][dx], a3);
        }
        size_t idx = (size_t)((((b * 64 + y) * 4 + g) * 10 + j) * 4 + qq) * 64
                     + l16 * 4;
        *(f32x4*)&x_ws[idx] = f32x4{a0 * SC1, a1 * SC1, a2 * SC1, a3 * SC2};
    }
}

// ---------------------------------------------------------------------------
__global__ __launch_bounds__(640, 3) void rnn_kernel(
        const float* __restrict__ x_ws, const __bf16* __restrict__ wsA,
        float* __restrict__ hid_ws, unsigned* __restrict__ halo_ws,
        unsigned* __restrict__ flags) {
    // state, transposed [col 0..17][ch 0..47]; col0/17 = halos; ch40 == 1.0
    // +16 tail pad on each bf16 array: every b128 read stays in-bounds
    // (max overshoot 15 elems from k=48..63 reads whose A-weights are 0).
    __shared__ __align__(16) __bf16 hC[18 * 48 + 16];
    __shared__ __align__(16) __bf16 cC[18 * 48 + 16];
    __shared__ __align__(16) __bf16 hL[2 * 768 + 16];  // [buf][col][ch]
    __shared__ float cwf[40 * 16];                     // conv c' fp32

    const int bid = blockIdx.x, g = bid & 3, b = bid >> 2;
    const int tid = threadIdx.x, wv = tid >> 6, lane = tid & 63;
    const int q = lane >> 4, l16 = lane & 15, cc = 4 * wv + q;
    const int W0 = g * 16;

    // ---- init LDS: zero everything (correct float extents incl. pads) ----
    for (int i = tid; i < 440; i += 640) {   // 880 bf16 = 440 floats
        ((float*)hC)[i] = 0.0f;
        ((float*)cC)[i] = 0.0f;
    }
    for (int i = tid; i < 776; i += 640)     // 1552 bf16 = 776 floats
        ((float*)hL)[i] = 0.0f;
    if (tid < 640) cwf[tid] = 0.0f;
    __syncthreads();                          // zeros done BEFORE ones
    if (tid < 18) { hC[tid * 48 + 40] = (__bf16)1.0f; cC[tid * 48 + 40] = (__bf16)1.0f; }
    if (tid < 32) hL[(tid >> 4) * 768 + (tid & 15) * 48 + 40] = (__bf16)1.0f;
    __syncthreads();

    // ---- preload fragments into registers ----
    bf16x8 a0c[7], a1c[7];
#pragma unroll
    for (int l = 0; l < 7; l++) {
        a0c[l] = *(const bf16x8*)&wsA[((l * 10 + wv) * 64 + lane) * 8];
        a1c[l] = *(const bf16x8*)&wsA[35840 + ((l * 10 + wv) * 64 + lane) * 8];
    }
    bf16x8 cva0[3], cva1[3];
    {
        int cv = (wv < 3) ? 0 : 1, mtc = (wv < 3) ? wv : wv - 3;
        int sel = (wv < 6) ? (cv * 3) : 0;   // dummy safe index for wv>=6
#pragma unroll
        for (int dx = 0; dx < 3; dx++) {
            int it = ((sel + dx) * 3 + ((wv < 6) ? mtc : 0));
            cva0[dx] = *(const bf16x8*)&wsA[71680 + (it * 64 + lane) * 8];
            cva1[dx] = *(const bf16x8*)&wsA[80896 + (it * 64 + lane) * 8];
        }
    }

    float c_reg = 0.0f;

    for (int t = 0; t < 64; t++) {
        // ---- x load (pre-scaled, coalesced f32x4/lane) ----
        f32x4 xv = *(const f32x4*)&x_ws[
            (size_t)((((b * 64 + t) * 4 + g) * 10 + wv) * 4 + q) * 64 + l16 * 4];

        // ---- phase A: 1x3 convs (waves 0..5) ----
        if (wv < 6) {
            const __bf16* st = (wv < 3) ? hC : cC;
            f32x4 acc = f32x4{0.f, 0.f, 0.f, 0.f};
#pragma unroll
            for (int dx = 0; dx < 3; dx++) {
                bf16x8 b0 = *(const bf16x8*)&st[(l16 + dx) * 48 + q * 8];
                bf16x8 b1 = *(const bf16x8*)&st[(l16 + dx) * 48 + 32 + q * 8];
                acc = __builtin_amdgcn_mfma_f32_16x16x32_bf16(cva0[dx], b0, acc, 0, 0, 0);
                acc = __builtin_amdgcn_mfma_f32_16x16x32_bf16(cva1[dx], b1, acc, 0, 0, 0);
            }
            int mtc = (wv < 3) ? wv : wv - 3;
            int ch0 = 16 * mtc + 4 * q;
            if (ch0 < 40) {
                if (wv < 3) {
                    bf16x4 hv;
#pragma unroll
                    for (int r = 0; r < 4; r++) hv[r] = (__bf16)acc[r];
                    *(bf16x4*)&hL[l16 * 48 + ch0] = hv;      // buf 0
                } else {
#pragma unroll
                    for (int r = 0; r < 4; r++) cwf[(ch0 + r) * 16 + l16] = acc[r];
                }
            }
        }
        BARRIER_LGKM();

        // ---- 7 layers ----
#pragma unroll
        for (int l = 0; l < 7; l++) {
            const __bf16* hb = &hL[(l & 1) * 768];
            bf16x8 b0 = *(const bf16x8*)&hb[l16 * 48 + q * 8];
            bf16x8 b1 = *(const bf16x8*)&hb[l16 * 48 + 32 + q * 8];
            f32x4 acc = __builtin_amdgcn_mfma_f32_16x16x32_bf16(
                a0c[l], b0, f32x4{0.f, 0.f, 0.f, 0.f}, 0, 0, 0);
            acc = __builtin_amdgcn_mfma_f32_16x16x32_bf16(a1c[l], b1, acc, 0, 0, 0);
            if (l == 0) c_reg = cwf[cc * 16 + l16];
            // pre-activations already scaled: arg_i = -log2e*v_i, etc.
            float Ei = __builtin_amdgcn_exp2f(fminf(acc[0] + xv[0], 44.f));
            float Ef = __builtin_amdgcn_exp2f(fminf(acc[1] + xv[1], 44.f));
            float Eo = __builtin_amdgcn_exp2f(fminf(acc[2] + xv[2], 44.f));
            float Eg = __builtin_amdgcn_exp2f(fminf(acc[3] + xv[3], 44.f));
            float f = __builtin_amdgcn_rcpf(1.0f + Ef);
            float ig = (1.0f - Eg) * __builtin_amdgcn_rcpf((1.0f + Ei) * (1.0f + Eg));
            float c = __builtin_fmaf(f, c_reg, ig);
            c_reg = c;
            float Ec = __builtin_amdgcn_exp2f(fminf(SC2 * c, 44.f));
            float h = (1.0f - Ec) * __builtin_amdgcn_rcpf((1.0f + Eo) * (1.0f + Ec));
            if (l < 6) {
                hL[((l + 1) & 1) * 768 + l16 * 48 + cc] = (__bf16)h;
                BARRIER_LGKM();
            } else {
                hC[(l16 + 1) * 48 + cc] = (__bf16)h;
                cC[(l16 + 1) * 48 + cc] = (__bf16)c;
                hid_ws[(size_t)((b * 64 + t) * 40 + cc) * 64 + W0 + l16] = h;
                if (t < 63) {
                    unsigned short hb16 = __builtin_bit_cast(unsigned short, (__bf16)h);
                    unsigned short cb16 = __builtin_bit_cast(unsigned short, (__bf16)c);
                    unsigned pk = (unsigned)hb16 | ((unsigned)cb16 << 16);
                    if (l16 == 0 && g > 0)
                        __hip_atomic_store(
                            &halo_ws[((bid * 2 + 0) * 2 + (t & 1)) * 40 + cc], pk,
                            __ATOMIC_RELAXED, __HIP_MEMORY_SCOPE_AGENT);
                    if (l16 == 15 && g < 3)
                        __hip_atomic_store(
                            &halo_ws[((bid * 2 + 1) * 2 + (t & 1)) * 40 + cc], pk,
                            __ATOMIC_RELAXED, __HIP_MEMORY_SCOPE_AGENT);
                }
                BARRIER_ALL();   // drains each wave's halo/hid stores
            }
        }

        // ---- publish flag; ingest neighbor halos for row t+1 ----
        if (t < 63) {
            if (tid == 0) {
                __threadfence();
                __hip_atomic_store(&flags[bid], (unsigned)(t + 1),
                                   __ATOMIC_RELEASE, __HIP_MEMORY_SCOPE_AGENT);
            }
            const unsigned want = (unsigned)(t + 1);
            if (wv == 0 && g > 0 && lane < 40) {
                unsigned f = __hip_atomic_load(&flags[bid - 1],
                    __ATOMIC_ACQUIRE, __HIP_MEMORY_SCOPE_AGENT);
                while (f - want > 1u) {
                    __builtin_amdgcn_s_sleep(2);
                    f = __hip_atomic_load(&flags[bid - 1],
                        __ATOMIC_ACQUIRE, __HIP_MEMORY_SCOPE_AGENT);
                }
                unsigned u = __hip_atomic_load(
                    &halo_ws[(((bid - 1) * 2 + 1) * 2 + (t & 1)) * 40 + lane],
                    __ATOMIC_RELAXED, __HIP_MEMORY_SCOPE_AGENT);
                hC[lane] = __builtin_bit_cast(__bf16, (unsigned short)(u & 0xffffu));
                cC[lane] = __builtin_bit_cast(__bf16, (unsigned short)(u >> 16));
            }
            if (wv == 1 && g < 3 && lane < 40) {
                unsigned f = __hip_atomic_load(&flags[bid + 1],
                    __ATOMIC_ACQUIRE, __HIP_MEMORY_SCOPE_AGENT);
                while (f - want > 1u) {
                    __builtin_amdgcn_s_sleep(2);
                    f = __hip_atomic_load(&flags[bid + 1],
                        __ATOMIC_ACQUIRE, __HIP_MEMORY_SCOPE_AGENT);
                }
                unsigned u = __hip_atomic_load(
                    &halo_ws[(((bid + 1) * 2 + 0) * 2 + (t & 1)) * 40 + lane],
                    __ATOMIC_RELAXED, __HIP_MEMORY_SCOPE_AGENT);
                hC[17 * 48 + lane] = __builtin_bit_cast(__bf16, (unsigned short)(u & 0xffffu));
                cC[17 * 48 + lane] = __builtin_bit_cast(__bf16, (unsigned short)(u >> 16));
            }
            BARRIER_LGKM();
        }
    }
}

// ---------------------------------------------------------------------------
__global__ __launch_bounds__(256) void out_kernel(
        const float* __restrict__ hid_ws, const float* __restrict__ w_out,
        const float* __restrict__ b_out, float* __restrict__ out) {
    __shared__ float wlds[40 * 264];   // transposed [k][o]
    __shared__ float hlds[40 * 64];
    int b = blockIdx.x >> 6, y = blockIdx.x & 63;
    int tid = threadIdx.x;
    for (int i = tid; i < 10240; i += 256) {
        int o = i / 40, k = i - o * 40;
        wlds[k * 264 + o] = w_out[i];
    }
    const float* hbp = hid_ws + (size_t)(b * 64 + y) * 40 * 64;
    for (int i = tid; i < 2560; i += 256) hlds[i] = hbp[i];
    __syncthreads();

    int tn = tid & 7, tm = tid >> 3;
    int wbase = tn * 8, obase = tm * 8;
    float acc[8][8];
#pragma unroll
    for (int io = 0; io < 8; io++)
#pragma unroll
        for (int iw = 0; iw < 8; iw++) acc[io][iw] = 0.0f;

    for (int k = 0; k < 40; k++) {
        f32x4 hA = *(const f32x4*)&hlds[k * 64 + wbase];
        f32x4 hB = *(const f32x4*)&hlds[k * 64 + wbase + 4];
        f32x4 wA = *(const f32x4*)&wlds[k * 264 + obase];
        f32x4 wB = *(const f32x4*)&wlds[k * 264 + obase + 4];
#pragma unroll
        for (int io = 0; io < 8; io++) {
            float wo = (io < 4) ? wA[io] : wB[io - 4];
#pragma unroll
            for (int iw = 0; iw < 8; iw++) {
                float hx = (iw < 4) ? hA[iw] : hB[iw - 4];
                acc[io][iw] = __builtin_fmaf(wo, hx, acc[io][iw]);
            }
        }
    }
#pragma unroll
    for (int io = 0; io < 8; io++) {
        int o = obase + io;
        float bo = b_out[o];
        f32x4 s0, s1;
#pragma unroll
        for (int iw = 0; iw < 4; iw++)
            s0[iw] = fmaxf(acc[io][iw] + bo, 0.0f);
#pragma unroll
        for (int iw = 0; iw < 4; iw++)
            s1[iw] = fmaxf(acc[io][iw + 4] + bo, 0.0f);
        float* ob = out + (size_t)((b * 256 + o) * 64 + y) * 64 + wbase;
        *(f32x4*)ob = s0;
        *(f32x4*)(ob + 4) = s1;
    }
}

// ---------------------------------------------------------------------------
extern "C" void kernel_launch(void* const* d_in, const int* in_sizes, int n_in,
                              void* d_out, int out_size, void* d_ws,
                              size_t ws_size, hipStream_t stream) {
    const float* input  = (const float*)d_in[0];
    const float* target = (const float*)d_in[1];
    const float* w_is   = (const float*)d_in[2];
    const float* b_is   = (const float*)d_in[3];
    const float* w_cis  = (const float*)d_in[4];
    const float* b_cis  = (const float*)d_in[5];
    const float* w_rh   = (const float*)d_in[6];
    const float* b_rh   = (const float*)d_in[7];
    const float* w_rc   = (const float*)d_in[8];
    const float* b_rc   = (const float*)d_in[9];
    const float* w_cell = (const float*)d_in[10];
    const float* b_cell = (const float*)d_in[11];
    const float* w_out  = (const float*)d_in[12];
    const float* b_out  = (const float*)d_in[13];
    float* out = (float*)d_out;

    char* ws = (char*)d_ws;
    float*    x_ws    = (float*)ws;                     // 41,943,040 B
    float*    hid_ws  = (float*)(ws + 41943040);        // 10,485,760 B
    __bf16*   wsA     = (__bf16*)(ws + 52428800);       //    180,224 B
    unsigned* halo_ws = (unsigned*)(ws + 52609024);     //     40,960 B
    unsigned* flags   = (unsigned*)(ws + 52649984);     //        256 B

    prep_kernel<<<352, 256, 0, stream>>>(w_cell, w_rh, w_rc, b_cell, b_rh,
                                         b_rc, wsA);
    conv7_kernel<<<1024, 256, 0, stream>>>(input, target, w_is, b_is, w_cis,
                                           b_cis, x_ws);
    rnn_kernel<<<64, 640, 0, stream>>>(x_ws, wsA, hid_ws, halo_ws, flags);
    out_kernel<<<1024, 256, 0, stream>>>(hid_ws, w_out, b_out, out);
}

// Round 6
// 407.184 us; speedup vs baseline: 3.5565x; 1.5507x over previous
//
#include <hip/hip_runtime.h>

// ---------------------------------------------------------------------------
// RowLSTM on MI355X — round 6: cheap inter-block handshake.
//  - Halo = ONE packed 64-bit agent atomic per channel: (tag=t)<<32 | c<<16 | h.
//    Self-validating word -> no threadfence, no flag, no release/acquire,
//    no vmcnt(0) drain anywhere in the row loop (x-load wait self-drains).
//  - bid swizzle: bid = g*16+b -> same-batch neighbors share bid%8 (same XCD
//    under round-robin dispatch) -> halo atomics stay XCD-local.
//  - One barrier at end-of-row (l6 writes + wv8/9 poll write disjoint LDS).
//  - x double-buffered in regs: row t+1's load issued at top of row t.
// Carried from round 5: A-fragments in registers, bias folded via constant
// channel h[40]=1, exp2-prescaled weights/x, lgkm-only barriers, 64 blocks
// (b,g) x 640 thr, lane-local gates.
// ---------------------------------------------------------------------------

typedef __bf16 bf16x8 __attribute__((ext_vector_type(8)));
typedef __bf16 bf16x4 __attribute__((ext_vector_type(4)));
typedef float  f32x4  __attribute__((ext_vector_type(4)));

#define SC1 (-1.44269504089f)   // -log2(e)
#define SC2 (-2.88539008178f)   // -2 log2(e)

#define BARRIER_LGKM() __asm__ volatile("s_waitcnt lgkmcnt(0)\ns_barrier" ::: "memory")

// ---------------------------------------------------------------------------
// wsA (bf16 elems):
//  [0     ,35840) cell a0 : [(l*10+mt)][lane][j]  k=q*8+j, row=r*40+4mt+(m>>2)
//                           scaled by (r==3 ? SC2 : SC1)
//  [35840 ,71680) cell a1x: [(l*10+mt)][lane][j]  k=32+q*8+j; k<40 weight,
//                           k==40 bias (b_cell), else 0; same scale
//  [71680 ,80896) conv a0 : [(cv*9+dx*3+mtc)][lane][j]  ch=16mtc+m (unscaled)
//  [80896 ,90112) conv a1x: same idx; k<40 weight, k==40&&dx==1 bias, else 0
__global__ __launch_bounds__(256) void prep_kernel(
        const float* __restrict__ wcell, const float* __restrict__ wrh,
        const float* __restrict__ wrc, const float* __restrict__ bcell,
        const float* __restrict__ brh, const float* __restrict__ brc,
        __bf16* __restrict__ wsA) {
    int i = blockIdx.x * 256 + threadIdx.x;
    if (i >= 90112) return;
    float val = 0.0f;
    if (i < 35840) {                       // cell a0
        int j = i & 7, lane = (i >> 3) & 63, lm = i >> 9;
        int mt = lm % 10, l = lm / 10;
        int k = (lane >> 4) * 8 + j, m = lane & 15, r = m & 3;
        int row = r * 40 + 4 * mt + (m >> 2);
        val = wcell[(l * 160 + row) * 40 + k] * (r == 3 ? SC2 : SC1);
    } else if (i < 71680) {                // cell a1 ext
        int i2 = i - 35840;
        int j = i2 & 7, lane = (i2 >> 3) & 63, lm = i2 >> 9;
        int mt = lm % 10, l = lm / 10;
        int k = 32 + (lane >> 4) * 8 + j, m = lane & 15, r = m & 3;
        int row = r * 40 + 4 * mt + (m >> 2);
        float s = (r == 3 ? SC2 : SC1);
        if (k < 40)       val = wcell[(l * 160 + row) * 40 + k] * s;
        else if (k == 40) val = bcell[l * 160 + row] * s;
    } else if (i < 80896) {                // conv a0
        int i3 = i - 71680;
        int j = i3 & 7, lane = (i3 >> 3) & 63, idx = i3 >> 9;   // 0..17
        int mtc = idx % 3, t2 = idx / 3, dx = t2 % 3, cv = t2 / 3;
        int k = (lane >> 4) * 8 + j;
        int ch = 16 * mtc + (lane & 15);
        const float* w = cv ? wrc : wrh;       // [40][40][1][3]
        if (ch < 40) val = w[(ch * 40 + k) * 3 + dx];
    } else {                               // conv a1 ext
        int i4 = i - 80896;
        int j = i4 & 7, lane = (i4 >> 3) & 63, idx = i4 >> 9;
        int mtc = idx % 3, t2 = idx / 3, dx = t2 % 3, cv = t2 / 3;
        int k = 32 + (lane >> 4) * 8 + j;
        int ch = 16 * mtc + (lane & 15);
        if (ch < 40) {
            const float* w = cv ? wrc : wrh;
            if (k < 40)                    val = w[(ch * 40 + k) * 3 + dx];
            else if (k == 40 && dx == 1)   val = (cv ? brc : brh)[ch];
        }
    }
    wsA[i] = (__bf16)val;
}

// ---------------------------------------------------------------------------
// x_ws (float, PRE-SCALED): [b][t][g4][mt10][q4][l16][gate4]
__global__ __launch_bounds__(256) void conv7_kernel(
        const float* __restrict__ inp, const float* __restrict__ tgt,
        const float* __restrict__ w_is, const float* __restrict__ b_is,
        const float* __restrict__ w_cis, const float* __restrict__ b_cis,
        float* __restrict__ x_ws) {
    int b = blockIdx.x >> 6, y = blockIdx.x & 63;
    int tid = threadIdx.x, qq = tid >> 6, w = tid & 63;
    const float* ib = inp + b * 4096;
    const float* tb = tgt + b * 4096;
    float pin[7][7], ptg[4][7];
#pragma unroll
    for (int dy = 0; dy < 7; dy++) {
        int yy = y + dy - 3;
#pragma unroll
        for (int dx = 0; dx < 7; dx++) {
            int xx = w + dx - 3;
            bool ok = (yy >= 0 && yy < 64 && xx >= 0 && xx < 64);
            pin[dy][dx] = ok ? ib[yy * 64 + xx] : 0.0f;
            if (dy < 4) ptg[dy][dx] = ok ? tb[yy * 64 + xx] : 0.0f;
        }
    }
    int g = w >> 4, l16 = w & 15;
    for (int j = 0; j < 10; j++) {
        int cc = 4 * j + qq;
        float a0 = b_cis[cc], a1 = b_cis[40 + cc];
        float a2 = b_is[cc], a3 = b_is[40 + cc];
        const float* w0 = w_cis + cc * 49;
        const float* w1 = w_cis + (40 + cc) * 49;
        const float* w2 = w_is + cc * 49;
        const float* w3 = w_is + (40 + cc) * 49;
#pragma unroll
        for (int dy = 0; dy < 7; dy++)
#pragma unroll
            for (int dx = 0; dx < 7; dx++) {
                a0 = __builtin_fmaf(w0[dy * 7 + dx], pin[dy][dx], a0);
                a1 = __builtin_fmaf(w1[dy * 7 + dx], pin[dy][dx], a1);
            }
#pragma unroll
        for (int dy = 0; dy < 3; dy++)
#pragma unroll
            for (int dx = 0; dx < 7; dx++) {
                a2 = __builtin_fmaf(w2[dy * 7 + dx], ptg[dy][dx], a2);
                a3 = __builtin_fmaf(w3[dy * 7 + dx], ptg[dy][dx], a3);
            }
#pragma unroll
        for (int dx = 0; dx < 3; dx++) {
            a2 = __builtin_fmaf(w2[21 + dx], ptg[3][dx], a2);
            a3 = __builtin_fmaf(w3[21 + dx], ptg[3][dx], a3);
        }
        size_t idx = (size_t)((((b * 64 + y) * 4 + g) * 10 + j) * 4 + qq) * 64
                     + l16 * 4;
        *(f32x4*)&x_ws[idx] = f32x4{a0 * SC1, a1 * SC1, a2 * SC1, a3 * SC2};
    }
}

// ---------------------------------------------------------------------------
// rnn: 64 blocks, bid = g*16 + b (same-batch neighbors share bid%8 -> XCD).
// halo_ws (u64): [bid][side2][parity2][ch40]; word = tag<<32 | c16<<16 | h16.
__global__ __launch_bounds__(640, 1) void rnn_kernel(
        const float* __restrict__ x_ws, const __bf16* __restrict__ wsA,
        float* __restrict__ hid_ws,
        unsigned long long* __restrict__ halo_ws) {
    // state, transposed [col 0..17][ch 0..47]; col0/17 = halos; ch40 == 1.0
    // +16 tail pad on each bf16 array: every b128 read stays in-bounds.
    __shared__ __align__(16) __bf16 hC[18 * 48 + 16];
    __shared__ __align__(16) __bf16 cC[18 * 48 + 16];
    __shared__ __align__(16) __bf16 hL[2 * 768 + 16];  // [buf][col][ch]
    __shared__ float cwf[40 * 16];                     // conv c' fp32

    const int bid = blockIdx.x, g = bid >> 4, b = bid & 15;
    const int tid = threadIdx.x, wv = tid >> 6, lane = tid & 63;
    const int q = lane >> 4, l16 = lane & 15, cc = 4 * wv + q;
    const int W0 = g * 16;

    // ---- init LDS ----
    for (int i = tid; i < 440; i += 640) {   // 880 bf16 = 440 floats
        ((float*)hC)[i] = 0.0f;
        ((float*)cC)[i] = 0.0f;
    }
    for (int i = tid; i < 776; i += 640)     // 1552 bf16 = 776 floats
        ((float*)hL)[i] = 0.0f;
    if (tid < 640) cwf[tid] = 0.0f;
    __syncthreads();                          // zeros done BEFORE ones
    if (tid < 18) { hC[tid * 48 + 40] = (__bf16)1.0f; cC[tid * 48 + 40] = (__bf16)1.0f; }
    if (tid < 32) hL[(tid >> 4) * 768 + (tid & 15) * 48 + 40] = (__bf16)1.0f;
    __syncthreads();

    // ---- preload fragments into registers ----
    bf16x8 a0c[7], a1c[7];
#pragma unroll
    for (int l = 0; l < 7; l++) {
        a0c[l] = *(const bf16x8*)&wsA[((l * 10 + wv) * 64 + lane) * 8];
        a1c[l] = *(const bf16x8*)&wsA[35840 + ((l * 10 + wv) * 64 + lane) * 8];
    }
    bf16x8 cva0[3], cva1[3];
    {
        int cv = (wv < 3) ? 0 : 1, mtc = (wv < 3) ? wv : wv - 3;
        int sel = (wv < 6) ? (cv * 3) : 0;
#pragma unroll
        for (int dx = 0; dx < 3; dx++) {
            int it = ((sel + dx) * 3 + ((wv < 6) ? mtc : 0));
            cva0[dx] = *(const bf16x8*)&wsA[71680 + (it * 64 + lane) * 8];
            cva1[dx] = *(const bf16x8*)&wsA[80896 + (it * 64 + lane) * 8];
        }
    }

    float c_reg = 0.0f;
    const size_t xstride = 10240;   // floats per (b,t)
    const size_t xbase0 = (size_t)(b * 64) * xstride
        + (((size_t)g * 10 + wv) * 4 + q) * 64 + l16 * 4;
    f32x4 xv = *(const f32x4*)&x_ws[xbase0];   // row 0

    for (int t = 0; t < 64; t++) {
        // ---- prefetch x for row t+1 (held in regs, waited at first use) ----
        f32x4 xn = xv;
        if (t < 63) xn = *(const f32x4*)&x_ws[xbase0 + (size_t)(t + 1) * xstride];

        // ---- phase A: 1x3 convs (waves 0..5) ----
        if (wv < 6) {
            const __bf16* st = (wv < 3) ? hC : cC;
            f32x4 acc = f32x4{0.f, 0.f, 0.f, 0.f};
#pragma unroll
            for (int dx = 0; dx < 3; dx++) {
                bf16x8 b0 = *(const bf16x8*)&st[(l16 + dx) * 48 + q * 8];
                bf16x8 b1 = *(const bf16x8*)&st[(l16 + dx) * 48 + 32 + q * 8];
                acc = __builtin_amdgcn_mfma_f32_16x16x32_bf16(cva0[dx], b0, acc, 0, 0, 0);
                acc = __builtin_amdgcn_mfma_f32_16x16x32_bf16(cva1[dx], b1, acc, 0, 0, 0);
            }
            int mtc = (wv < 3) ? wv : wv - 3;
            int ch0 = 16 * mtc + 4 * q;
            if (ch0 < 40) {
                if (wv < 3) {
                    bf16x4 hv;
#pragma unroll
                    for (int r = 0; r < 4; r++) hv[r] = (__bf16)acc[r];
                    *(bf16x4*)&hL[l16 * 48 + ch0] = hv;      // buf 0
                } else {
#pragma unroll
                    for (int r = 0; r < 4; r++) cwf[(ch0 + r) * 16 + l16] = acc[r];
                }
            }
        }
        BARRIER_LGKM();

        // ---- 7 layers ----
#pragma unroll
        for (int l = 0; l < 7; l++) {
            const __bf16* hb = &hL[(l & 1) * 768];
            bf16x8 b0 = *(const bf16x8*)&hb[l16 * 48 + q * 8];
            bf16x8 b1 = *(const bf16x8*)&hb[l16 * 48 + 32 + q * 8];
            f32x4 acc = __builtin_amdgcn_mfma_f32_16x16x32_bf16(
                a0c[l], b0, f32x4{0.f, 0.f, 0.f, 0.f}, 0, 0, 0);
            acc = __builtin_amdgcn_mfma_f32_16x16x32_bf16(a1c[l], b1, acc, 0, 0, 0);
            if (l == 0) c_reg = cwf[cc * 16 + l16];
            float Ei = __builtin_amdgcn_exp2f(fminf(acc[0] + xv[0], 44.f));
            float Ef = __builtin_amdgcn_exp2f(fminf(acc[1] + xv[1], 44.f));
            float Eo = __builtin_amdgcn_exp2f(fminf(acc[2] + xv[2], 44.f));
            float Eg = __builtin_amdgcn_exp2f(fminf(acc[3] + xv[3], 44.f));
            float f = __builtin_amdgcn_rcpf(1.0f + Ef);
            float ig = (1.0f - Eg) * __builtin_amdgcn_rcpf((1.0f + Ei) * (1.0f + Eg));
            float c = __builtin_fmaf(f, c_reg, ig);
            c_reg = c;
            float Ec = __builtin_amdgcn_exp2f(fminf(SC2 * c, 44.f));
            float h = (1.0f - Ec) * __builtin_amdgcn_rcpf((1.0f + Eo) * (1.0f + Ec));
            if (l < 6) {
                hL[((l + 1) & 1) * 768 + l16 * 48 + cc] = (__bf16)h;
                BARRIER_LGKM();
            } else {
                hC[(l16 + 1) * 48 + cc] = (__bf16)h;
                cC[(l16 + 1) * 48 + cc] = (__bf16)c;
                hid_ws[(size_t)((b * 64 + t) * 40 + cc) * 64 + W0 + l16] = h;
                if (t < 63) {
                    unsigned short h16 = __builtin_bit_cast(unsigned short, (__bf16)h);
                    unsigned short c16 = __builtin_bit_cast(unsigned short, (__bf16)c);
                    unsigned long long v = ((unsigned long long)(unsigned)t << 32)
                        | ((unsigned)c16 << 16) | (unsigned)h16;
                    if (l16 == 0 && g > 0)
                        __hip_atomic_store(
                            &halo_ws[((bid * 2 + 0) * 2 + (t & 1)) * 40 + cc], v,
                            __ATOMIC_RELAXED, __HIP_MEMORY_SCOPE_AGENT);
                    if (l16 == 15 && g < 3)
                        __hip_atomic_store(
                            &halo_ws[((bid * 2 + 1) * 2 + (t & 1)) * 40 + cc], v,
                            __ATOMIC_RELAXED, __HIP_MEMORY_SCOPE_AGENT);
                }
                // no barrier here: merged with post-poll barrier below
            }
        }

        // ---- ingest neighbor halos for row t+1 (wv8: left, wv9: right) ----
        if (t < 63) {
            if (wv == 8 && g > 0 && lane < 40) {
                const unsigned long long* src =
                    &halo_ws[(((bid - 16) * 2 + 1) * 2 + (t & 1)) * 40 + lane];
                unsigned long long v = __hip_atomic_load(
                    src, __ATOMIC_RELAXED, __HIP_MEMORY_SCOPE_AGENT);
                while ((unsigned)(v >> 32) != (unsigned)t) {
                    __builtin_amdgcn_s_sleep(1);
                    v = __hip_atomic_load(src, __ATOMIC_RELAXED,
                                          __HIP_MEMORY_SCOPE_AGENT);
                }
                hC[lane] = __builtin_bit_cast(__bf16, (unsigned short)(v & 0xffffu));
                cC[lane] = __builtin_bit_cast(__bf16, (unsigned short)((v >> 16) & 0xffffu));
            }
            if (wv == 9 && g < 3 && lane < 40) {
                const unsigned long long* src =
                    &halo_ws[(((bid + 16) * 2 + 0) * 2 + (t & 1)) * 40 + lane];
                unsigned long long v = __hip_atomic_load(
                    src, __ATOMIC_RELAXED, __HIP_MEMORY_SCOPE_AGENT);
                while ((unsigned)(v >> 32) != (unsigned)t) {
                    __builtin_amdgcn_s_sleep(1);
                    v = __hip_atomic_load(src, __ATOMIC_RELAXED,
                                          __HIP_MEMORY_SCOPE_AGENT);
                }
                hC[17 * 48 + lane] = __builtin_bit_cast(__bf16, (unsigned short)(v & 0xffffu));
                cC[17 * 48 + lane] = __builtin_bit_cast(__bf16, (unsigned short)((v >> 16) & 0xffffu));
            }
        }
        BARRIER_LGKM();   // single end-of-row barrier (l6 writes + halo cols)
        xv = xn;
    }
}

// ---------------------------------------------------------------------------
__global__ __launch_bounds__(256) void out_kernel(
        const float* __restrict__ hid_ws, const float* __restrict__ w_out,
        const float* __restrict__ b_out, float* __restrict__ out) {
    __shared__ float wlds[40 * 264];   // transposed [k][o]
    __shared__ float hlds[40 * 64];
    int b = blockIdx.x >> 6, y = blockIdx.x & 63;
    int tid = threadIdx.x;
    for (int i = tid; i < 10240; i += 256) {
        int o = i / 40, k = i - o * 40;
        wlds[k * 264 + o] = w_out[i];
    }
    const float* hbp = hid_ws + (size_t)(b * 64 + y) * 40 * 64;
    for (int i = tid; i < 2560; i += 256) hlds[i] = hbp[i];
    __syncthreads();

    int tn = tid & 7, tm = tid >> 3;
    int wbase = tn * 8, obase = tm * 8;
    float acc[8][8];
#pragma unroll
    for (int io = 0; io < 8; io++)
#pragma unroll
        for (int iw = 0; iw < 8; iw++) acc[io][iw] = 0.0f;

    for (int k = 0; k < 40; k++) {
        f32x4 hA = *(const f32x4*)&hlds[k * 64 + wbase];
        f32x4 hB = *(const f32x4*)&hlds[k * 64 + wbase + 4];
        f32x4 wA = *(const f32x4*)&wlds[k * 264 + obase];
        f32x4 wB = *(const f32x4*)&wlds[k * 264 + obase + 4];
#pragma unroll
        for (int io = 0; io < 8; io++) {
            float wo = (io < 4) ? wA[io] : wB[io - 4];
#pragma unroll
            for (int iw = 0; iw < 8; iw++) {
                float hx = (iw < 4) ? hA[iw] : hB[iw - 4];
                acc[io][iw] = __builtin_fmaf(wo, hx, acc[io][iw]);
            }
        }
    }
#pragma unroll
    for (int io = 0; io < 8; io++) {
        int o = obase + io;
        float bo = b_out[o];
        f32x4 s0, s1;
#pragma unroll
        for (int iw = 0; iw < 4; iw++)
            s0[iw] = fmaxf(acc[io][iw] + bo, 0.0f);
#pragma unroll
        for (int iw = 0; iw < 4; iw++)
            s1[iw] = fmaxf(acc[io][iw + 4] + bo, 0.0f);
        float* ob = out + (size_t)((b * 256 + o) * 64 + y) * 64 + wbase;
        *(f32x4*)ob = s0;
        *(f32x4*)(ob + 4) = s1;
    }
}

// ---------------------------------------------------------------------------
extern "C" void kernel_launch(void* const* d_in, const int* in_sizes, int n_in,
                              void* d_out, int out_size, void* d_ws,
                              size_t ws_size, hipStream_t stream) {
    const float* input  = (const float*)d_in[0];
    const float* target = (const float*)d_in[1];
    const float* w_is   = (const float*)d_in[2];
    const float* b_is   = (const float*)d_in[3];
    const float* w_cis  = (const float*)d_in[4];
    const float* b_cis  = (const float*)d_in[5];
    const float* w_rh   = (const float*)d_in[6];
    const float* b_rh   = (const float*)d_in[7];
    const float* w_rc   = (const float*)d_in[8];
    const float* b_rc   = (const float*)d_in[9];
    const float* w_cell = (const float*)d_in[10];
    const float* b_cell = (const float*)d_in[11];
    const float* w_out  = (const float*)d_in[12];
    const float* b_out  = (const float*)d_in[13];
    float* out = (float*)d_out;

    char* ws = (char*)d_ws;
    float*              x_ws    = (float*)ws;                        // 41,943,040 B
    float*              hid_ws  = (float*)(ws + 41943040);           // 10,485,760 B
    __bf16*             wsA     = (__bf16*)(ws + 52428800);          //    180,224 B
    unsigned long long* halo_ws = (unsigned long long*)(ws + 52609024); // 81,920 B

    prep_kernel<<<352, 256, 0, stream>>>(w_cell, w_rh, w_rc, b_cell, b_rh,
                                         b_rc, wsA);
    conv7_kernel<<<1024, 256, 0, stream>>>(input, target, w_is, b_is, w_cis,
                                           b_cis, x_ws);
    rnn_kernel<<<64, 640, 0, stream>>>(x_ws, wsA, hid_ws, halo_ws);
    out_kernel<<<1024, 256, 0, stream>>>(hid_ws, w_out, b_out, out);
}